// Round 1
// baseline (484.017 us; speedup 1.0000x reference)
//
#include <hip/hip_runtime.h>

// out[b,c,x] = sum_i M[c,i] * x[b,i,x], with
//   M[c,i] = Re( sum_k T[c,k] e^{-2pi i k i/512} ),
//   T[c,k] = (1/512) sum_o (wr[k,o] + i wi[k,o]) e^{+2pi i o c/512}
// k_m1: row-wise inverse FFT of w  -> T (ws)
// k_m2: row-wise forward FFT of T  -> Re -> bf16, packed in MFMA A-frag order (ws)
// k_gemm: bf16 MFMA GEMM, x staged to LDS as bf16 (read x once, write out once)

typedef float f32x4 __attribute__((ext_vector_type(4)));
typedef short s16x8 __attribute__((ext_vector_type(8)));

#define PI_F 3.14159265358979f

__device__ __forceinline__ unsigned short f2bf(float f) {
  unsigned int u = __float_as_uint(f);
  u = (u + 0x7fffu + ((u >> 16) & 1u)) >> 16;  // RNE, inputs never NaN
  return (unsigned short)u;
}

// ---------------- M1: T[c][k] = ifft_o(w[k,:])[c] ----------------
__global__ __launch_bounds__(256) void k_m1(const float* __restrict__ wr,
                                            const float* __restrict__ wi,
                                            float2* __restrict__ T) {
  __shared__ float ar[512];
  __shared__ float ai[512];
  const int k = blockIdx.x;
  const int t = threadIdx.x;
#pragma unroll
  for (int h = 0; h < 2; ++h) {
    int o = t + h * 256;
    int p = (int)(__brev((unsigned)o) >> 23);  // 9-bit reverse
    ar[p] = wr[k * 512 + o];
    ai[p] = wi[k * 512 + o];
  }
  __syncthreads();
#pragma unroll
  for (int s = 0; s < 9; ++s) {
    const int m = 1 << s;
    const int j = t & (m - 1);
    const int g = t >> s;
    const int i0 = (g << (s + 1)) + j;
    const int i1 = i0 + m;
    float sn, cs;
    sincosf(PI_F * (float)j / (float)m, &sn, &cs);
    // inverse FFT twiddle: W = cs + i*sn
    const float xr = ar[i1], xi = ai[i1];
    const float tr = xr * cs - xi * sn;
    const float ti = xr * sn + xi * cs;
    const float yr = ar[i0], yi = ai[i0];
    ar[i0] = yr + tr; ai[i0] = yi + ti;
    ar[i1] = yr - tr; ai[i1] = yi - ti;
    __syncthreads();
  }
#pragma unroll
  for (int h = 0; h < 2; ++h) {
    int c = t + h * 256;
    T[(size_t)c * 512 + k] = make_float2(ar[c] * (1.0f / 512.0f),
                                         ai[c] * (1.0f / 512.0f));
  }
}

// ---------------- M2: M[c][i] = Re(fft_k(T[c,:]))[i], pack bf16 A-frags ----------------
__global__ __launch_bounds__(256) void k_m2(const float2* __restrict__ T,
                                            unsigned short* __restrict__ Mp) {
  __shared__ float ar[512];
  __shared__ float ai[512];
  const int c = blockIdx.x;
  const int t = threadIdx.x;
#pragma unroll
  for (int h = 0; h < 2; ++h) {
    int kq = t + h * 256;
    int p = (int)(__brev((unsigned)kq) >> 23);
    float2 v = T[(size_t)c * 512 + kq];
    ar[p] = v.x;
    ai[p] = v.y;
  }
  __syncthreads();
#pragma unroll
  for (int s = 0; s < 9; ++s) {
    const int m = 1 << s;
    const int j = t & (m - 1);
    const int g = t >> s;
    const int i0 = (g << (s + 1)) + j;
    const int i1 = i0 + m;
    float sn, cs;
    sincosf(PI_F * (float)j / (float)m, &sn, &cs);
    // forward FFT twiddle: W = cs - i*sn
    const float xr = ar[i1], xi = ai[i1];
    const float tr = xr * cs + xi * sn;
    const float ti = xi * cs - xr * sn;
    const float yr = ar[i0], yi = ai[i0];
    ar[i0] = yr + tr; ai[i0] = yi + ti;
    ar[i1] = yr - tr; ai[i1] = yi - ti;
    __syncthreads();
  }
  // Pack M[c][i] (bf16) into A-fragment order for mfma_f32_16x16x32_bf16:
  // lane = (c&15) + 16*((i>>3)&3), elem j = i&7, row-block rB=c>>4, k-step kk=i>>5
#pragma unroll
  for (int h = 0; h < 2; ++h) {
    int i = t + h * 256;
    unsigned short v = f2bf(ar[i]);
    int rB = c >> 4;
    int kk = i >> 5;
    int lane = (c & 15) + 16 * ((i >> 3) & 3);
    int j = i & 7;
    Mp[(size_t)(((rB * 16 + kk) * 64 + lane) * 8 + j)] = v;
  }
}

// ---------------- GEMM: out[b, 0:512, xoff:xoff+64] = M @ x[b, :, xoff:xoff+64] ----------------
__global__ __launch_bounds__(512, 4) void k_gemm(const float* __restrict__ x,
                                                 const unsigned short* __restrict__ Mp,
                                                 float* __restrict__ out) {
  // x-tile in bf16, cell layout [kh=64][c=64][8 elems along k] = 64 KiB
  __shared__ unsigned short xlds[64 * 64 * 8];
  const int tid = threadIdx.x;
  const int bid = blockIdx.x;
  const int b = bid >> 6;
  const int xoff = (bid & 63) << 6;
  const float* xb = x + ((size_t)b * 512 * 4096 + xoff);

  // ---- stage x (fp32 -> bf16) ----
  {
    const int tk = tid & 31;        // k within 32-chunk
    const int c = (tid >> 5) * 4;   // 4 consecutive columns per thread
#pragma unroll
    for (int i = 0; i < 16; ++i) {
      const int k = i * 32 + tk;
      const float4 v = *(const float4*)(xb + (size_t)k * 4096 + c);
      const int base = ((k >> 3) * 64 + c) * 8 + (k & 7);
      xlds[base +  0] = f2bf(v.x);
      xlds[base +  8] = f2bf(v.y);
      xlds[base + 16] = f2bf(v.z);
      xlds[base + 24] = f2bf(v.w);
    }
  }
  __syncthreads();

  const int w = tid >> 6;        // wave 0..7 -> rows [64w, 64w+64)
  const int lane = tid & 63;
  const int lrow = lane & 15;
  const int lk = lane >> 4;
  const int ldsb = lk * 512 + lrow * 8;  // ushort units
  float* ob = out + ((size_t)b * 512 * 4096 + xoff);

#pragma unroll
  for (int half = 0; half < 2; ++half) {  // row-split: 32 rows per pass -> low VGPR
    const unsigned short* mph =
        Mp + ((size_t)w * 32768 + (size_t)half * 16384 + (size_t)lane * 8);
    f32x4 acc[2][4] = {};
#pragma unroll
    for (int kk = 0; kk < 16; ++kk) {
      const s16x8 b0 = *(const s16x8*)&xlds[ldsb + kk * 2048 +   0];
      const s16x8 b1 = *(const s16x8*)&xlds[ldsb + kk * 2048 + 128];
      const s16x8 b2 = *(const s16x8*)&xlds[ldsb + kk * 2048 + 256];
      const s16x8 b3 = *(const s16x8*)&xlds[ldsb + kk * 2048 + 384];
      const s16x8 a0 = *(const s16x8*)(mph + kk * 512);
      const s16x8 a1 = *(const s16x8*)(mph + 8192 + kk * 512);
      acc[0][0] = __builtin_amdgcn_mfma_f32_16x16x32_bf16(a0, b0, acc[0][0], 0, 0, 0);
      acc[0][1] = __builtin_amdgcn_mfma_f32_16x16x32_bf16(a0, b1, acc[0][1], 0, 0, 0);
      acc[0][2] = __builtin_amdgcn_mfma_f32_16x16x32_bf16(a0, b2, acc[0][2], 0, 0, 0);
      acc[0][3] = __builtin_amdgcn_mfma_f32_16x16x32_bf16(a0, b3, acc[0][3], 0, 0, 0);
      acc[1][0] = __builtin_amdgcn_mfma_f32_16x16x32_bf16(a1, b0, acc[1][0], 0, 0, 0);
      acc[1][1] = __builtin_amdgcn_mfma_f32_16x16x32_bf16(a1, b1, acc[1][1], 0, 0, 0);
      acc[1][2] = __builtin_amdgcn_mfma_f32_16x16x32_bf16(a1, b2, acc[1][2], 0, 0, 0);
      acc[1][3] = __builtin_amdgcn_mfma_f32_16x16x32_bf16(a1, b3, acc[1][3], 0, 0, 0);
    }
    // C/D layout (m89-verified): col = lane&15, row = (lane>>4)*4 + reg
#pragma unroll
    for (int rbl = 0; rbl < 2; ++rbl) {
      const int row0 = w * 64 + half * 32 + rbl * 16 + lk * 4;
#pragma unroll
      for (int cb = 0; cb < 4; ++cb) {
#pragma unroll
        for (int q = 0; q < 4; ++q) {
          ob[(size_t)(row0 + q) * 4096 + cb * 16 + lrow] = acc[rbl][cb][q];
        }
      }
    }
  }
}

extern "C" void kernel_launch(void* const* d_in, const int* in_sizes, int n_in,
                              void* d_out, int out_size, void* d_ws, size_t ws_size,
                              hipStream_t stream) {
  const float* x  = (const float*)d_in[0];
  const float* wr = (const float*)d_in[1];
  const float* wi = (const float*)d_in[2];
  float* out = (float*)d_out;

  // workspace: T (512*512 float2 = 2 MiB) then Mp (512*512 bf16 = 512 KiB)
  float2* T = (float2*)d_ws;
  unsigned short* Mp = (unsigned short*)((char*)d_ws + (size_t)(2 * 1024 * 1024));

  k_m1<<<512, 256, 0, stream>>>(wr, wi, T);
  k_m2<<<512, 256, 0, stream>>>(T, Mp);
  k_gemm<<<2048, 512, 0, stream>>>(x, Mp, out);
}